// Round 2
// baseline (1179.439 us; speedup 1.0000x reference)
//
#include <hip/hip_runtime.h>
#include <hip/hip_bf16.h>

// ---------------------------------------------------------------------------
// Fused causal attention block (x @ Wqkv^T -> flash attn -> @ Wout^T), fp32 I/O.
// All matmuls on MFMA via bf16 hi/lo split (3 products) for ~fp32 accuracy.
// B=2, S=2048, D=2048, H=16, Dh=128.
// ---------------------------------------------------------------------------

typedef __attribute__((ext_vector_type(4))) float f32x4;
typedef __attribute__((ext_vector_type(8))) short s16x8;
typedef __attribute__((ext_vector_type(4))) short s16x4;

static constexpr int Bx   = 2;
static constexpr int Sx   = 2048;
static constexpr int Dm   = 2048;
static constexpr int NHx  = 16;
static constexpr int DHx  = 128;
static constexpr int Mtot = Bx * Sx;   // 4096
static constexpr int Kdim = Dm;        // 2048
static constexpr int Nqkv = 3 * Dm;    // 6144

#define LOG2E 1.4426950408889634f
#define NEG_INF (-__builtin_inff())
#define MFMA16(a, b, c) __builtin_amdgcn_mfma_f32_16x16x32_bf16((a), (b), (c), 0, 0, 0)

__device__ __forceinline__ float bf2f(short h) {
  unsigned u = ((unsigned)(unsigned short)h) << 16;
  return __builtin_bit_cast(float, u);
}
__device__ __forceinline__ short f2bf(float f) {  // round-to-nearest-even
  unsigned u = __builtin_bit_cast(unsigned, f);
  u += 0x7FFFu + ((u >> 16) & 1u);
  return (short)(u >> 16);
}
__device__ __forceinline__ void gl_lds16(const void* g, void* l) {
  __builtin_amdgcn_global_load_lds(
      (__attribute__((address_space(1))) void*)g,
      (__attribute__((address_space(3))) void*)l, 16, 0, 0);
}

// ---------------------------------------------------------------------------
// fp32 -> (hi, lo) bf16 split, vectorized x4
// ---------------------------------------------------------------------------
__global__ void split_f32_bf16(const float* __restrict__ in, short* __restrict__ hi,
                               short* __restrict__ lo, int n4) {
  int i = blockIdx.x * blockDim.x + threadIdx.x;
  if (i >= n4) return;
  f32x4 v = ((const f32x4*)in)[i];
  s16x4 h, l;
#pragma unroll
  for (int j = 0; j < 4; ++j) {
    short hh = f2bf(v[j]);
    h[j] = hh;
    l[j] = f2bf(v[j] - bf2f(hh));
  }
  ((s16x4*)hi)[i] = h;
  ((s16x4*)lo)[i] = l;
}

// ---------------------------------------------------------------------------
// Split-bf16 GEMM: C[m,n] = sum_k A[m,k]*B[n,k] + bias[n]   (A: MxK, B: NxK)
// 128x128 tile, BK=64, 4 waves (2x2) of 64x64, mfma 16x16x32.
// LDS XOR-swizzle (row&7)<<4 applied via pre-swizzled global source for
// global_load_lds (linear dest) + swizzled ds_read (rule 21 / T2).
// EPI=0: scatter to q/k/v hi/lo (B,H,S,Dh).  EPI=1: fp32 out (M x 2048) + bias.
// ---------------------------------------------------------------------------
template <int EPI>
__global__ __launch_bounds__(256) void gemm_split(
    const short* __restrict__ Ah, const short* __restrict__ Al,
    const short* __restrict__ Bh, const short* __restrict__ Bl,
    const float* __restrict__ bias, float* __restrict__ outF,
    short* __restrict__ qh, short* __restrict__ ql, short* __restrict__ kh,
    short* __restrict__ kl, short* __restrict__ vh, short* __restrict__ vl) {
  __shared__ short lds[4 * 8192];  // 64 KB: [A_hi][A_lo][B_hi][B_lo], each 128x64 bf16

  const int tid  = threadIdx.x;
  const int lane = tid & 63;
  const int wid  = tid >> 6;
  const int wr   = wid >> 1, wc = wid & 1;
  const int bn   = blockIdx.x, bm = blockIdx.y;

  f32x4 acc[4][4];
#pragma unroll
  for (int i = 0; i < 4; ++i)
#pragma unroll
    for (int j = 0; j < 4; ++j) acc[i][j] = f32x4{0.f, 0.f, 0.f, 0.f};

  const int rowA = bm * 128, rowB = bn * 128;

  for (int kt = 0; kt < Kdim / 64; ++kt) {
    const int k0 = kt * 64;
    // ---- stage 4 tiles (A_hi, A_lo, B_hi, B_lo), each 16 KB ----
#pragma unroll
    for (int t = 0; t < 4; ++t) {
      const short* src = (t == 0) ? Ah : (t == 1) ? Al : (t == 2) ? Bh : Bl;
      const int rbase  = (t < 2) ? rowA : rowB;
#pragma unroll
      for (int i = 0; i < 4; ++i) {
        const int L = wid * 4096 + i * 1024 + lane * 16;   // linear LDS byte
        const int G = L ^ (((L >> 7) & 7) << 4);           // swizzled logical byte
        const char* gsrc = (const char*)src +
                           (size_t)(rbase + (G >> 7)) * (size_t)(Kdim * 2) +
                           (size_t)(k0 * 2) + (G & 127);
        gl_lds16(gsrc, (char*)lds + t * 16384 + wid * 4096 + i * 1024);
      }
    }
    __syncthreads();
    // ---- compute: 2 K=32 substeps, 3 split products each ----
#pragma unroll
    for (int ks = 0; ks < 2; ++ks) {
      s16x8 afh[4], afl[4], bfh[4], bfl[4];
#pragma unroll
      for (int mi = 0; mi < 4; ++mi) {
        const int row = wr * 64 + mi * 16 + (lane & 15);
        const int off = (row * 128 + ks * 64 + (lane >> 4) * 16) ^ ((row & 7) << 4);
        afh[mi] = *(const s16x8*)((const char*)lds + off);
        afl[mi] = *(const s16x8*)((const char*)lds + 16384 + off);
      }
#pragma unroll
      for (int nj = 0; nj < 4; ++nj) {
        const int row = wc * 64 + nj * 16 + (lane & 15);
        const int off = (row * 128 + ks * 64 + (lane >> 4) * 16) ^ ((row & 7) << 4);
        bfh[nj] = *(const s16x8*)((const char*)lds + 32768 + off);
        bfl[nj] = *(const s16x8*)((const char*)lds + 49152 + off);
      }
#pragma unroll
      for (int mi = 0; mi < 4; ++mi)
#pragma unroll
        for (int nj = 0; nj < 4; ++nj)
          acc[mi][nj] = MFMA16(afh[mi], bfh[nj], acc[mi][nj]);
#pragma unroll
      for (int mi = 0; mi < 4; ++mi)
#pragma unroll
        for (int nj = 0; nj < 4; ++nj)
          acc[mi][nj] = MFMA16(afh[mi], bfl[nj], acc[mi][nj]);
#pragma unroll
      for (int mi = 0; mi < 4; ++mi)
#pragma unroll
        for (int nj = 0; nj < 4; ++nj)
          acc[mi][nj] = MFMA16(afl[mi], bfh[nj], acc[mi][nj]);
    }
    __syncthreads();
  }
  // ---- epilogue ----
#pragma unroll
  for (int mi = 0; mi < 4; ++mi) {
#pragma unroll
    for (int nj = 0; nj < 4; ++nj) {
      const int n  = bn * 128 + wc * 64 + nj * 16 + (lane & 15);
      const float bv = bias[n];
#pragma unroll
      for (int r = 0; r < 4; ++r) {
        const int m = bm * 128 + wr * 64 + mi * 16 + (lane >> 4) * 4 + r;
        const float val = acc[mi][nj][r] + bv;
        if (EPI == 1) {
          outF[(size_t)m * 2048 + n] = val;
        } else {
          const int which = n >> 11, rr = n & 2047;
          const int h = rr >> 7, d = rr & 127;
          const int b = m >> 11, s = m & 2047;
          const size_t idx = ((size_t)(b * 16 + h) * 2048 + s) * 128 + d;
          const short h16 = f2bf(val);
          const short l16 = f2bf(val - bf2f(h16));
          if (which == 0) { qh[idx] = h16; ql[idx] = l16; }
          else if (which == 1) { kh[idx] = h16; kl[idx] = l16; }
          else { vh[idx] = h16; vl[idx] = l16; }
        }
      }
    }
  }
}

// ---------------------------------------------------------------------------
// Flash causal attention with mask, split-bf16 MFMA, online softmax (fp32).
// Block: 4 waves x 16 q-rows (QBLK=64); KV tile = 32. Causal tile skipping.
// ctx written as hi/lo bf16 into (M=B*S, D) row-major for the out-GEMM.
// ---------------------------------------------------------------------------
__global__ __launch_bounds__(256) void attn_split(
    const short* __restrict__ qh, const short* __restrict__ ql,
    const short* __restrict__ kh, const short* __restrict__ kl,
    const short* __restrict__ vh, const short* __restrict__ vl,
    const float* __restrict__ mask, short* __restrict__ ctx_hi,
    short* __restrict__ ctx_lo) {
  __shared__ short Kls[2][4096];      // hi/lo K tile, 32x128 bf16, swizzled storage
  __shared__ short VT[2][128][40];    // hi/lo V^T tile (pad 40 for banks/alignment)
  __shared__ short Pls[2][4][640];    // hi/lo P per wave: 16 x 40

  const int tid = threadIdx.x, lane = tid & 63, wid = tid >> 6;
  const int qt = blockIdx.x, hh = blockIdx.y, bb = blockIdx.z;
  const size_t bhoff = (size_t)(bb * NHx + hh) * (size_t)(Sx * DHx);
  const int q0 = qt * 64 + wid * 16;
  const float kScale = 0.08838834764831845f;  // 1/sqrt(128)

  // Q fragments in registers (A-operand): lane holds Q[q0+(lane&15)][ks*32+(lane>>4)*8 ..+8]
  s16x8 qfh[4], qfl[4];
#pragma unroll
  for (int ks = 0; ks < 4; ++ks) {
    const size_t o = bhoff + (size_t)(q0 + (lane & 15)) * 128 + ks * 32 + (lane >> 4) * 8;
    qfh[ks] = *(const s16x8*)(qh + o);
    qfl[ks] = *(const s16x8*)(ql + o);
  }

  f32x4 acc[8];
#pragma unroll
  for (int dt = 0; dt < 8; ++dt) acc[dt] = f32x4{0.f, 0.f, 0.f, 0.f};
  float mrow[4] = {NEG_INF, NEG_INF, NEG_INF, NEG_INF};
  float lrow[4] = {0.f, 0.f, 0.f, 0.f};

  const int ntiles = qt * 2 + 2;  // causal: kv tiles 0 .. (block max row)/32
  for (int t = 0; t < ntiles; ++t) {
    const int kv0 = t * 32;
    // ---- stage K hi/lo via swizzled global_load_lds (tile is contiguous) ----
#pragma unroll
    for (int p = 0; p < 2; ++p) {
      const short* src = p ? kl : kh;
#pragma unroll
      for (int i = 0; i < 2; ++i) {
        const int L = wid * 2048 + i * 1024 + lane * 16;
        const int G = L ^ (((L >> 8) & 7) << 4);
        const char* gsrc = (const char*)src + (bhoff + (size_t)kv0 * 128) * 2 + G;
        gl_lds16(gsrc, (char*)Kls + p * 8192 + wid * 2048 + i * 1024);
      }
    }
    // ---- stage V^T hi/lo via register transpose ----
    {
      const int kv = tid & 31, d0 = (tid >> 5) * 16;
      const size_t o = bhoff + (size_t)(kv0 + kv) * 128 + d0;
      s16x8 a0 = *(const s16x8*)(vh + o);
      s16x8 a1 = *(const s16x8*)(vh + o + 8);
      s16x8 b0 = *(const s16x8*)(vl + o);
      s16x8 b1 = *(const s16x8*)(vl + o + 8);
#pragma unroll
      for (int j = 0; j < 8; ++j) {
        VT[0][d0 + j][kv]     = a0[j];
        VT[0][d0 + 8 + j][kv] = a1[j];
        VT[1][d0 + j][kv]     = b0[j];
        VT[1][d0 + 8 + j][kv] = b1[j];
      }
    }
    __syncthreads();

    // ---- QK^T: scores for 16 q-rows x 32 kv, split products ----
    f32x4 sc[2];
#pragma unroll
    for (int st = 0; st < 2; ++st) {
      f32x4 a = f32x4{0.f, 0.f, 0.f, 0.f};
#pragma unroll
      for (int ks = 0; ks < 4; ++ks) {
        const int row = st * 16 + (lane & 15);
        const int off = (row * 256 + ks * 64 + (lane >> 4) * 16) ^ ((row & 7) << 4);
        s16x8 kfh = *(const s16x8*)((const char*)Kls + off);
        s16x8 kfl = *(const s16x8*)((const char*)Kls + 8192 + off);
        a = MFMA16(qfh[ks], kfh, a);
        a = MFMA16(qfh[ks], kfl, a);
        a = MFMA16(qfl[ks], kfh, a);
      }
      sc[st] = a;
    }

    // ---- online softmax (fp32) ----
    float s0[4], s1[4], rmax[4];
#pragma unroll
    for (int r = 0; r < 4; ++r) {
      const int qr = q0 + (lane >> 4) * 4 + r;
      const int c0 = kv0 + (lane & 15);
      const int c1 = c0 + 16;
      const float* mp = mask + ((size_t)hh * Sx + qr) * Sx;
      s0[r] = sc[0][r] * kScale + mp[c0];
      s1[r] = sc[1][r] * kScale + mp[c1];
      if (c0 > qr) s0[r] = NEG_INF;
      if (c1 > qr) s1[r] = NEG_INF;
      rmax[r] = fmaxf(s0[r], s1[r]);
    }
#pragma unroll
    for (int off = 1; off <= 8; off <<= 1)
#pragma unroll
      for (int r = 0; r < 4; ++r)
        rmax[r] = fmaxf(rmax[r], __shfl_xor(rmax[r], off, 64));

    float corr[4];
#pragma unroll
    for (int r = 0; r < 4; ++r) {
      const float mnew = fmaxf(mrow[r], rmax[r]);
      // fmaxf(..., -100) also sanitizes (-inf - -inf)=NaN -> -100 -> exp ~ 0
      corr[r] = exp2f(fmaxf(mrow[r] - mnew, -100.f) * LOG2E);
      const float p0 = exp2f(fmaxf(s0[r] - mnew, -100.f) * LOG2E);
      const float p1 = exp2f(fmaxf(s1[r] - mnew, -100.f) * LOG2E);
      mrow[r] = mnew;
      const short p0h = f2bf(p0), p1h = f2bf(p1);
      const short p0l = f2bf(p0 - bf2f(p0h)), p1l = f2bf(p1 - bf2f(p1h));
      const int qlidx = ((lane >> 4) * 4 + r) * 40;
      Pls[0][wid][qlidx + (lane & 15)]      = p0h;
      Pls[0][wid][qlidx + 16 + (lane & 15)] = p1h;
      Pls[1][wid][qlidx + (lane & 15)]      = p0l;
      Pls[1][wid][qlidx + 16 + (lane & 15)] = p1l;
      float rs = p0 + p1;
#pragma unroll
      for (int off = 1; off <= 8; off <<= 1) rs += __shfl_xor(rs, off, 64);
      lrow[r] = lrow[r] * corr[r] + rs;
    }
#pragma unroll
    for (int dt = 0; dt < 8; ++dt)
#pragma unroll
      for (int r = 0; r < 4; ++r) acc[dt][r] *= corr[r];

    __syncthreads();  // P visibility across lanes (conservative)

    // ---- P·V ----
    const char* pbh = (const char*)&Pls[0][wid][0] + (lane & 15) * 80 + (lane >> 4) * 16;
    const char* pbl = (const char*)&Pls[1][wid][0] + (lane & 15) * 80 + (lane >> 4) * 16;
    s16x8 pfh = *(const s16x8*)pbh;
    s16x8 pfl = *(const s16x8*)pbl;
#pragma unroll
    for (int dt = 0; dt < 8; ++dt) {
      const int drow = dt * 16 + (lane & 15);
      s16x8 vfh = *(const s16x8*)&VT[0][drow][(lane >> 4) * 8];
      s16x8 vfl = *(const s16x8*)&VT[1][drow][(lane >> 4) * 8];
      acc[dt] = MFMA16(pfh, vfh, acc[dt]);
      acc[dt] = MFMA16(pfh, vfl, acc[dt]);
      acc[dt] = MFMA16(pfl, vfh, acc[dt]);
    }
    __syncthreads();  // all waves done with Kls/VT before next-tile staging
  }

  // ---- epilogue: ctx = acc / l, write hi/lo bf16 into (M, D) row-major ----
#pragma unroll
  for (int dt = 0; dt < 8; ++dt) {
#pragma unroll
    for (int r = 0; r < 4; ++r) {
      const float val = acc[dt][r] / lrow[r];
      const int m = bb * Sx + qt * 64 + wid * 16 + (lane >> 4) * 4 + r;
      const int c = hh * 128 + dt * 16 + (lane & 15);
      const size_t idx = (size_t)m * 2048 + c;
      const short h16 = f2bf(val);
      const short l16 = f2bf(val - bf2f(h16));
      ctx_hi[idx] = h16;
      ctx_lo[idx] = l16;
    }
  }
}

// ---------------------------------------------------------------------------
// launch
// ---------------------------------------------------------------------------
extern "C" void kernel_launch(void* const* d_in, const int* in_sizes, int n_in,
                              void* d_out, int out_size, void* d_ws, size_t ws_size,
                              hipStream_t stream) {
  (void)in_sizes; (void)n_in; (void)out_size; (void)ws_size;
  const float* x    = (const float*)d_in[0];
  const float* mask = (const float*)d_in[1];
  const float* Wqkv = (const float*)d_in[2];
  const float* bqkv = (const float*)d_in[3];
  const float* Wout = (const float*)d_in[4];
  const float* bout = (const float*)d_in[5];
  float* out = (float*)d_out;

  // workspace carve (~192 MiB total)
  char* w = (char*)d_ws;
  auto alloc = [&](size_t bytes) {
    char* p = w;
    w += (bytes + 255) & ~(size_t)255;
    return p;
  };
  const size_t xB   = (size_t)Mtot * Kdim * 2;   // 16.78 MB
  const size_t wqB  = (size_t)Nqkv * Kdim * 2;   // 25.17 MB
  const size_t woB  = (size_t)Dm * Kdim * 2;     // 8.39 MB
  const size_t qkvB = (size_t)Bx * NHx * Sx * DHx * 2;  // 16.78 MB

  short* x_hi = (short*)alloc(xB);
  short* x_lo = (short*)alloc(xB);
  short* Wqkv_hi = (short*)alloc(wqB);
  short* Wqkv_lo = (short*)alloc(wqB);
  short* Wout_hi = (short*)alloc(woB);
  short* Wout_lo = (short*)alloc(woB);
  short* q_hi = (short*)alloc(qkvB);
  short* q_lo = (short*)alloc(qkvB);
  short* k_hi = (short*)alloc(qkvB);
  short* k_lo = (short*)alloc(qkvB);
  short* v_hi = (short*)alloc(qkvB);
  short* v_lo = (short*)alloc(qkvB);
  // ctx reuses x region: x dead after QKV GEMM, attn runs after it (same stream)
  short* ctx_hi = x_hi;
  short* ctx_lo = x_lo;

  // 1) fp32 -> bf16 hi/lo splits
  split_f32_bf16<<<(Mtot * Kdim / 4) / 256, 256, 0, stream>>>(x, x_hi, x_lo, Mtot * Kdim / 4);
  split_f32_bf16<<<(Nqkv * Kdim / 4) / 256, 256, 0, stream>>>(Wqkv, Wqkv_hi, Wqkv_lo, Nqkv * Kdim / 4);
  split_f32_bf16<<<(Dm * Kdim / 4) / 256, 256, 0, stream>>>(Wout, Wout_hi, Wout_lo, Dm * Kdim / 4);

  // 2) QKV GEMM -> q/k/v hi/lo (B,H,S,Dh)
  gemm_split<0><<<dim3(Nqkv / 128, Mtot / 128), 256, 0, stream>>>(
      x_hi, x_lo, Wqkv_hi, Wqkv_lo, bqkv, nullptr,
      q_hi, q_lo, k_hi, k_lo, v_hi, v_lo);

  // 3) flash causal attention -> ctx hi/lo (M, D)
  attn_split<<<dim3(Sx / 64, NHx, Bx), 256, 0, stream>>>(
      q_hi, q_lo, k_hi, k_lo, v_hi, v_lo, mask, ctx_hi, ctx_lo);

  // 4) output GEMM -> d_out (fp32)
  gemm_split<1><<<dim3(Dm / 128, Mtot / 128), 256, 0, stream>>>(
      ctx_hi, ctx_lo, Wout_hi, Wout_lo, bout, out,
      nullptr, nullptr, nullptr, nullptr, nullptr, nullptr);
}